// Round 6
// baseline (3538.637 us; speedup 1.0000x reference)
//
#include <hip/hip_runtime.h>
#include <hip/hip_bf16.h>

#define B_ 64
#define T_ 512
#define D_ 256
#define H_ 1024
#define RING 64          // h-history ring depth
#define PS 260           // partial row stride in floats

typedef __attribute__((ext_vector_type(8))) short short8;
typedef __attribute__((ext_vector_type(4))) float floatx4;

__device__ __forceinline__ unsigned short f2bf(float f){
  unsigned u = __builtin_bit_cast(unsigned, f);
  u = (u + 0x7fffu + ((u >> 16) & 1u)) >> 16;
  return (unsigned short)u;
}

__device__ __forceinline__ short8 pack8(floatx4 a, floatx4 b){
  short8 r;
  r[0]=(short)f2bf(a[0]); r[1]=(short)f2bf(a[1]); r[2]=(short)f2bf(a[2]); r[3]=(short)f2bf(a[3]);
  r[4]=(short)f2bf(b[0]); r[5]=(short)f2bf(b[1]); r[6]=(short)f2bf(b[2]); r[7]=(short)f2bf(b[3]);
  return r;
}

__device__ __forceinline__ float sigm(float v){ return 1.f/(1.f+__expf(-v)); }
__device__ __forceinline__ float tanh_f(float v){ return 1.f - 2.f/(1.f+__expf(2.f*v)); }

// Pollster-wave global poll over 64 producer qwords (8 lines), with a monotone
// in-register cache: already-covered targets cost zero memory ops.
__device__ __forceinline__ void gpoll(const unsigned long long* watch,
                                      unsigned& seen0, unsigned& seen1,
                                      unsigned tgt0, unsigned tgt1){
  if (__all(seen0 >= tgt0 && seen1 >= tgt1)) return;
  long g = 0;
  for (;;){
    unsigned long long v = __hip_atomic_load(watch, __ATOMIC_RELAXED, __HIP_MEMORY_SCOPE_AGENT);
    unsigned v0 = (unsigned)v, v1 = (unsigned)(v >> 32);
    seen0 = v0 > seen0 ? v0 : seen0;
    seen1 = v1 > seen1 ? v1 : seen1;
    if (__all(seen0 >= tgt0 && seen1 >= tgt1)) break;
    if (++g > (1L<<24)) break;   // safety valve; never hit in correct runs
  }
}

// LDS spin: zero fabric traffic for non-pollster waves.
__device__ __forceinline__ void lspin(unsigned* flag, unsigned tgt){
  long g = 0;
  while (__hip_atomic_load(flag, __ATOMIC_RELAXED, __HIP_MEMORY_SCOPE_WORKGROUP) < tgt){
    if (++g > (1L<<24)) break;
  }
}

// h ring layout: MFMA-fragment tiles. slot*(64*1024) + jblk*1024 + row*16 + col  [shorts]
// seq: one qword per producer (per half): lo dword = layer0 seq, hi = layer1 seq.
//
// Sync plane (r2 structure — each wave has exactly ONE wait; pollsters poll immediately):
//   L0: wave0 = ring guard only (its slice is all-x); wave1 polls peers (L0>=t) -> rdy[0];
//       waves2-7 lspin rdy[0].
//   L1: wave0 polls h0-fresh (L0>=t+1) -> rdy[0]; waves1-3 lspin rdy[0] (h0-region slices);
//       wave4 polls h1 peers (L1>=t) -> rdy[1]; waves5-7 lspin rdy[1] (h1-region slices).
//       h1-region waves run their full 8-k-step burst under L0's shadow.
//
// k-slice maps:
//   L0 (KW=160, NK=5): wave w owns k in [w*160, w*160+160). x part (k<256) computed
//       PRE-GATE (no recurrence dep, drains under the wait); h0 part post-gate.
//   L1 (KW=256, NK=8): wave w owns k in [w*256, w*256+256): waves0-3 pure h0-region,
//       waves4-7 pure h1-region.
template<int LAYER>
__device__ __forceinline__ void run_lstm(
    const float* __restrict__ x,
    const float* __restrict__ Wi, const float* __restrict__ Wh,
    const float* __restrict__ bi, const float* __restrict__ bh,
    unsigned* seq, unsigned short* h0h, unsigned short* h1h, float* h1f,
    int jbase, int j, int half,
    float* partial /*[64][PS]*/, float* c_st /*[32*16]*/, float* biasv /*[64]*/,
    unsigned* rdy /*[2] in LDS*/)
{
  constexpr int NK = LAYER ? 8 : 5;
  constexpr int KA = LAYER ? 1024 : 256;  // Wi K extent

  const int tid  = threadIdx.x;
  const int wave = tid >> 6;
  const int lane = tid & 63;
  const int n15  = lane & 15;
  const int kq   = (lane >> 4) * 8;

  // ---- one-time: weights -> registers (bf16) per the k-slice map.
  short8 bfr[4][NK];
  #pragma unroll
  for (int nt = 0; nt < 4; nt++){
    int n   = nt*16 + n15;
    int row = (n >> 4)*H_ + jbase + (n & 15);
    #pragma unroll
    for (int ks = 0; ks < NK; ks++){
      int k = (LAYER ? wave*256 + ks*32 : wave*160 + ks*32) + kq;
      const float* s = (k < KA) ? (Wi + (size_t)row*KA + k)
                                : (Wh + (size_t)row*H_ + (k - KA));
      bfr[nt][ks] = pack8(*(const floatx4*)s, *(const floatx4*)(s + 4));
    }
  }
  if (tid < 64){
    int col = (tid >> 4)*H_ + jbase + (tid & 15);
    biasv[tid] = bi[col] + bh[col];
  }
  c_st[tid & 511] = 0.f;
  if (tid == 0){ rdy[0] = 0u; rdy[1] = 0u; }
  __syncthreads();

  // pollster watch: lane l covers producer qword (half*64 + l)
  const unsigned long long* watch =
      (const unsigned long long*)seq + (size_t)(half*64 + lane);
  const bool isPoll = LAYER ? (wave == 0 || wave == 4) : (wave <= 1);

  unsigned seen0 = 0, seen1 = 0;
  unsigned long long vf = 0;       // tail-prefetched counter line (pollster waves)

  for (int t = 0; t < T_; t++){
    // merge tail prefetch into the monotone cache
    { unsigned p0 = (unsigned)vf, p1 = (unsigned)(vf >> 32);
      seen0 = p0 > seen0 ? p0 : seen0;
      seen1 = p1 > seen1 ? p1 : seen1; }

    floatx4 acc[2][4];
    #pragma unroll
    for (int mt = 0; mt < 2; mt++)
      #pragma unroll
      for (int nt = 0; nt < 4; nt++)
        acc[mt][nt] = (floatx4)0.f;

    const unsigned short* h0t = h0h + ((size_t)((LAYER ? t : (t-1)) & (RING-1)) << 16);
    const unsigned short* h1t = h1h + ((size_t)((t-1) & (RING-1)) << 16);

    if constexpr (LAYER == 0){
      // ---- x pass PRE-GATE: loads + packs + MFMAs drain under the wait
      __builtin_amdgcn_s_setprio(1);
      #pragma unroll
      for (int ks = 0; ks < NK; ks++){
        const int kb = wave*160 + ks*32;
        if (kb < D_){
          const int kk = kb + kq;
          short8 afr[2];
          #pragma unroll
          for (int mt = 0; mt < 2; mt++){
            const float* xs = x + ((size_t)(half*32 + mt*16 + n15)*T_ + t)*D_ + kk;
            afr[mt] = pack8(*(const floatx4*)xs, *(const floatx4*)(xs + 4));
          }
          #pragma unroll
          for (int mt = 0; mt < 2; mt++)
            #pragma unroll
            for (int nt = 0; nt < 4; nt++)
              acc[mt][nt] = __builtin_amdgcn_mfma_f32_16x16x32_bf16(afr[mt], bfr[nt][ks], acc[mt][nt], 0, 0, 0);
        }
      }
      __builtin_amdgcn_s_setprio(0);
      __builtin_amdgcn_sched_barrier(0);
      // ---- gate: wave0 = ring guard only; wave1 = peers pollster -> rdy[0]; others relay.
      if (wave == 0){
        gpoll(watch, seen0, seen1, 0u, (t >= RING) ? (unsigned)(t - RING + 1) : 0u);
      } else if (wave == 1){
        gpoll(watch, seen0, seen1, (unsigned)t, 0u);
        if (lane == 0) __hip_atomic_store(&rdy[0], (unsigned)(t + 1),
                                          __ATOMIC_RELAXED, __HIP_MEMORY_SCOPE_WORKGROUP);
      } else {
        lspin(&rdy[0], (unsigned)(t + 1));
      }
      __builtin_amdgcn_sched_barrier(0);
      // ---- h0 pass (post-gate), at elevated priority vs spinning siblings
      if (t > 0){
        __builtin_amdgcn_s_setprio(1);
        #pragma unroll
        for (int ks = 0; ks < NK; ks++){
          const int kb = wave*160 + ks*32;
          if (kb >= D_){
            const int hk = kb - D_ + kq;
            const unsigned short* p = h0t + ((hk >> 4) << 10) + (hk & 15);
            short8 afr[2];
            #pragma unroll
            for (int mt = 0; mt < 2; mt++)
              afr[mt] = *(const short8*)(p + ((half*32 + mt*16 + n15) << 4));
            #pragma unroll
            for (int mt = 0; mt < 2; mt++)
              #pragma unroll
              for (int nt = 0; nt < 4; nt++)
                acc[mt][nt] = __builtin_amdgcn_mfma_f32_16x16x32_bf16(afr[mt], bfr[nt][ks], acc[mt][nt], 0, 0, 0);
          }
        }
        __builtin_amdgcn_s_setprio(0);
      }
    } else {
      // ---- gates: one wait per wave, pollsters poll IMMEDIATELY (r2 structure)
      if (wave == 0){
        gpoll(watch, seen0, seen1, (unsigned)(t + 1), 0u);   // h0 fresh
        if (lane == 0) __hip_atomic_store(&rdy[0], (unsigned)(t + 1),
                                          __ATOMIC_RELAXED, __HIP_MEMORY_SCOPE_WORKGROUP);
      } else if (wave == 4){
        gpoll(watch, seen0, seen1, 0u, (unsigned)t);         // h1 peers
        if (lane == 0) __hip_atomic_store(&rdy[1], (unsigned)(t + 1),
                                          __ATOMIC_RELAXED, __HIP_MEMORY_SCOPE_WORKGROUP);
      } else if (wave < 4){
        lspin(&rdy[0], (unsigned)(t + 1));
      } else {
        lspin(&rdy[1], (unsigned)(t + 1));
      }
      __builtin_amdgcn_sched_barrier(0);
      // ---- full 8-k-step burst for this wave's region, at elevated priority
      __builtin_amdgcn_s_setprio(1);
      #pragma unroll
      for (int ks = 0; ks < NK; ks++){
        const int kb = wave*256 + ks*32;
        if (kb >= KA && t == 0) continue;   // h1[-1] = 0: skip (wave-uniform)
        const int kk = kb + kq;
        const int hk = (kb < 1024) ? kk : (kk - 1024);
        const unsigned short* sb = (kb < 1024) ? h0t : h1t;
        const unsigned short* p = sb + ((hk >> 4) << 10) + (hk & 15);
        short8 afr[2];
        #pragma unroll
        for (int mt = 0; mt < 2; mt++)
          afr[mt] = *(const short8*)(p + ((half*32 + mt*16 + n15) << 4));
        #pragma unroll
        for (int mt = 0; mt < 2; mt++)
          #pragma unroll
          for (int nt = 0; nt < 4; nt++)
            acc[mt][nt] = __builtin_amdgcn_mfma_f32_16x16x32_bf16(afr[mt], bfr[nt][ks], acc[mt][nt], 0, 0, 0);
      }
      __builtin_amdgcn_s_setprio(0);
    }

    // ---- spill K-slice partials: [n][wave*32+b] so 4 acc rows are one ds_write_b128
    #pragma unroll
    for (int mt = 0; mt < 2; mt++)
      #pragma unroll
      for (int nt = 0; nt < 4; nt++){
        int n  = nt*16 + n15;
        int b0 = mt*16 + (lane >> 4)*4;
        *(floatx4*)(partial + (size_t)n*PS + wave*32 + b0) = acc[mt][nt];
      }
    __syncthreads();

    // ---- gate reduction by ALL 512 threads: one (b, jj) each
    {
      int b = tid >> 4, jj = tid & 15;
      float g[4];
      #pragma unroll
      for (int q = 0; q < 4; q++){
        const float* p = partial + (size_t)(q*16 + jj)*PS + b;
        float s = biasv[q*16 + jj];
        #pragma unroll
        for (int ss = 0; ss < 8; ss++) s += p[ss*32];
        g[q] = s;
      }
      float co = c_st[tid];            // tid == b*16 + jj
      float si = sigm(g[0]), sf = sigm(g[1]), tg = tanh_f(g[2]), so = sigm(g[3]);
      float cn = sf*co + si*tg;
      float hn = so*tanh_f(cn);
      c_st[tid] = cn;
      unsigned hb = (unsigned)f2bf(hn);
      unsigned ob = (unsigned)__shfl_xor((int)hb, 1, 64);   // partner jj^1, same b
      if (!(jj & 1)){
        unsigned pk = hb | (ob << 16);
        unsigned short* dst = (LAYER ? h1h : h0h)
                            + ((size_t)(t & (RING-1)) << 16)
                            + ((size_t)j << 10) + ((size_t)(half*32 + b) << 4) + jj;
        __hip_atomic_store((unsigned*)dst, pk, __ATOMIC_RELAXED, __HIP_MEMORY_SCOPE_AGENT);
      }
      if (LAYER == 1 && t == T_-1)
        h1f[(size_t)(half*32 + b)*H_ + jbase + jj] = hn;
    }
    // pollster tail prefetch: completes under the barrier's vmcnt drain; often makes
    // the next step's poll free (seen-cache covers the target -> zero RTT).
    if (isPoll)
      vf = __hip_atomic_load(watch, __ATOMIC_RELAXED, __HIP_MEMORY_SCOPE_AGENT);
    __syncthreads();   // all waves drain vmcnt (h stores visible) before the post
    if (tid == 0)
      __hip_atomic_store(seq + (size_t)(half*64 + j)*2 + LAYER, (unsigned)(t + 1),
                         __ATOMIC_RELAXED, __HIP_MEMORY_SCOPE_AGENT);
  }
}

__global__ __launch_bounds__(512, 2) void lstm_pk(
    const float* __restrict__ x,
    const float* __restrict__ Wih0, const float* __restrict__ Whh0,
    const float* __restrict__ bih0, const float* __restrict__ bhh0,
    const float* __restrict__ Wih1, const float* __restrict__ Whh1,
    const float* __restrict__ bih1, const float* __restrict__ bhh1,
    char* __restrict__ ws)
{
  __shared__ __align__(16) float partial[64*PS];   // 66.6 KB
  __shared__ float c_st[512];
  __shared__ float biasv[64];
  __shared__ unsigned rdy[2];

  unsigned* seq       = (unsigned*)ws;                                    // 128 qwords (1 KB)
  unsigned short* h0h = (unsigned short*)(ws + (1<<20));                  // RING x 128KB tiles (8 MB)
  unsigned short* h1h = (unsigned short*)(ws + (1<<20) + RING*B_*H_*2);   // 8 MB
  float* h1f          = (float*)(ws + (1<<20) + 2*(size_t)RING*B_*H_*2);  // [64][1024] fp32

  const int bid = blockIdx.x;
  if (bid < 128){
    run_lstm<0>(x, Wih0, Whh0, bih0, bhh0, seq, h0h, h1h, h1f,
                (bid & 63)*16, bid & 63, bid >> 6, partial, c_st, biasv, rdy);
  } else {
    const int r = bid - 128;
    run_lstm<1>(x, Wih1, Whh1, bih1, bhh1, seq, h0h, h1h, h1f,
                (r & 63)*16, r & 63, r >> 6, partial, c_st, biasv, rdy);
  }
}

__global__ __launch_bounds__(128) void fc_k(
    const float* __restrict__ h1f, const float* __restrict__ Wfc,
    const float* __restrict__ bfc, float* __restrict__ out)
{
  __shared__ float hv[1024];
  int b = blockIdx.x, c = threadIdx.x;
  for (int i = c; i < 1024; i += 128) hv[i] = h1f[(size_t)b*1024 + i];
  __syncthreads();
  const floatx4* w4 = (const floatx4*)(Wfc + (size_t)c*1024);
  const floatx4* h4 = (const floatx4*)hv;
  float acc = 0.f;
  #pragma unroll 8
  for (int k = 0; k < 256; k++){
    floatx4 wv = w4[k];
    floatx4 hh = h4[k];
    acc += wv[0]*hh[0] + wv[1]*hh[1] + wv[2]*hh[2] + wv[3]*hh[3];
  }
  out[(size_t)b*128 + c] = acc + bfc[c];
}

extern "C" void kernel_launch(void* const* d_in, const int* in_sizes, int n_in,
                              void* d_out, int out_size, void* d_ws, size_t ws_size,
                              hipStream_t stream)
{
  const float* x    = (const float*)d_in[0];
  const float* Wih0 = (const float*)d_in[1];
  const float* Whh0 = (const float*)d_in[2];
  const float* bih0 = (const float*)d_in[3];
  const float* bhh0 = (const float*)d_in[4];
  const float* Wih1 = (const float*)d_in[5];
  const float* Whh1 = (const float*)d_in[6];
  const float* bih1 = (const float*)d_in[7];
  const float* bhh1 = (const float*)d_in[8];
  const float* Wfc  = (const float*)d_in[9];
  const float* bfc  = (const float*)d_in[10];

  // zero the seq counters (h ring slots written before first read; h[-1] by predication)
  hipMemsetAsync(d_ws, 0, 4096, stream);

  lstm_pk<<<256, 512, 0, stream>>>(x, Wih0, Whh0, bih0, bhh0, Wih1, Whh1, bih1, bhh1, (char*)d_ws);

  const float* h1f = (const float*)((char*)d_ws + (1<<20) + 2*(size_t)RING*B_*H_*2);
  fc_k<<<64, 128, 0, stream>>>(h1f, Wfc, bfc, (float*)d_out);
}

// Round 8
// 3088.068 us; speedup vs baseline: 1.1459x; 1.1459x over previous
//
#include <hip/hip_runtime.h>
#include <hip/hip_bf16.h>

#define B_ 64
#define T_ 512
#define D_ 256
#define H_ 1024
#define RING 64          // h-history ring depth
#define PS 260           // partial row stride in floats

typedef __attribute__((ext_vector_type(8))) short short8;
typedef __attribute__((ext_vector_type(4))) float floatx4;

__device__ __forceinline__ unsigned short f2bf(float f){
  unsigned u = __builtin_bit_cast(unsigned, f);
  u = (u + 0x7fffu + ((u >> 16) & 1u)) >> 16;
  return (unsigned short)u;
}

__device__ __forceinline__ short8 pack8(floatx4 a, floatx4 b){
  short8 r;
  r[0]=(short)f2bf(a[0]); r[1]=(short)f2bf(a[1]); r[2]=(short)f2bf(a[2]); r[3]=(short)f2bf(a[3]);
  r[4]=(short)f2bf(b[0]); r[5]=(short)f2bf(b[1]); r[6]=(short)f2bf(b[2]); r[7]=(short)f2bf(b[3]);
  return r;
}

__device__ __forceinline__ float sigm(float v){ return 1.f/(1.f+__expf(-v)); }
__device__ __forceinline__ float tanh_f(float v){ return 1.f - 2.f/(1.f+__expf(2.f*v)); }

// Pollster-wave global poll at ELEVATED PRIORITY: the detect loop is the step-period
// critical path for all 8 waves of the block -- let it win issue arbitration against
// sibling compute/spill bursts on the same CU.
__device__ __forceinline__ void gpoll(const unsigned long long* watch, unsigned tgt0, unsigned tgt1){
  if (!(tgt0 | tgt1)) return;
  __builtin_amdgcn_s_setprio(1);
  long g = 0;
  for (;;){
    unsigned long long v = __hip_atomic_load(watch, __ATOMIC_RELAXED, __HIP_MEMORY_SCOPE_AGENT);
    unsigned v0 = (unsigned)v, v1 = (unsigned)(v >> 32);
    if (__all(v0 >= tgt0 && v1 >= tgt1)) break;
    if (++g > (1L<<24)) break;   // safety valve; never hit in correct runs
  }
  __builtin_amdgcn_s_setprio(0);
}

// LDS spin: zero fabric traffic for non-pollster waves.
__device__ __forceinline__ void lspin(unsigned* flag, unsigned tgt){
  long g = 0;
  while (__hip_atomic_load(flag, __ATOMIC_RELAXED, __HIP_MEMORY_SCOPE_WORKGROUP) < tgt){
    if (++g > (1L<<24)) break;
  }
}

// h ring layout: MFMA-fragment tiles. slot*(64*1024) + jblk*1024 + row*16 + col  [shorts]
// seq layout: one qword per producer block j (per half): dword0 = layer0 seq, dword1 = layer1 seq.
//
// Sync plane (r2 structure, verbatim):
//   L0: wave0 polls ring guard (L1 counters), wave1 polls peers (L0 >= t) -> rdy[0];
//       waves2-7 lspin rdy[0].
//   L1: wave0 polls h0-fresh (L0 >= t+1) -> rdy[0]; waves1-3 lspin rdy[0];
//       wave4 polls h1 peers (L1 >= t) -> rdy[1]; waves5-7 lspin rdy[1].
template<int LAYER>
__device__ __forceinline__ void run_lstm(
    const float* __restrict__ x,
    const float* __restrict__ Wi, const float* __restrict__ Wh,
    const float* __restrict__ bi, const float* __restrict__ bh,
    unsigned* seq, unsigned short* h0h, unsigned short* h1h, float* h1f,
    int jbase, int j, int half,
    float* partial /*[64][PS]*/, float* c_st /*[32*16]*/, float* biasv /*[64]*/,
    unsigned* rdy /*[2] in LDS*/)
{
  constexpr int NK = LAYER ? 8 : 5;
  constexpr int KA = LAYER ? 1024 : 256;  // Wi K extent

  const int tid  = threadIdx.x;
  const int wave = tid >> 6;
  const int lane = tid & 63;
  const int n15  = lane & 15;
  const int kq   = (lane >> 4) * 8;

  // ---- one-time: weights -> registers (bf16). 4 n-tiles x NK k-steps per wave.
  short8 bfr[4][NK];
  #pragma unroll
  for (int nt = 0; nt < 4; nt++){
    int n   = nt*16 + n15;
    int row = (n >> 4)*H_ + jbase + (n & 15);
    #pragma unroll
    for (int ks = 0; ks < NK; ks++){
      int k = (LAYER ? wave*256 + ks*32 : wave*160 + ks*32) + kq;
      const float* s = (k < KA) ? (Wi + (size_t)row*KA + k)
                                : (Wh + (size_t)row*H_ + (k - KA));
      bfr[nt][ks] = pack8(*(const floatx4*)s, *(const floatx4*)(s + 4));
    }
  }
  if (tid < 64){
    int col = (tid >> 4)*H_ + jbase + (tid & 15);
    biasv[tid] = bi[col] + bh[col];
  }
  c_st[tid & 511] = 0.f;
  if (tid == 0){ rdy[0] = 0u; rdy[1] = 0u; }
  __syncthreads();

  // pollster watch: lane l covers producer qword (half*64 + l)
  const unsigned long long* watch =
      (const unsigned long long*)seq + (size_t)(half*64 + lane);

  for (int t = 0; t < T_; t++){
    // ---- L0: issue raw x loads BEFORE the poll (x[t] has no recurrence dep).
    // Keep raw fp32 in regs through the poll; pack after.  Latency hides under the wait.
    // NOTE: array must be NK deep -- wave 0's slice is ALL x (5 k-steps). (r7 bug: [2].)
    floatx4 xraw[LAYER ? 1 : NK][2][2];
    if constexpr (LAYER == 0){
      #pragma unroll
      for (int ks = 0; ks < NK; ks++){
        const int kb = wave*160 + ks*32;
        if (kb < D_){
          const int kk = kb + kq;
          #pragma unroll
          for (int mt = 0; mt < 2; mt++){
            const float* xs = x + ((size_t)(half*32 + mt*16 + n15)*T_ + t)*D_ + kk;
            xraw[ks][mt][0] = *(const floatx4*)xs;
            xraw[ks][mt][1] = *(const floatx4*)(xs + 4);
          }
        }
      }
    }

    // ---- dataflow sync (r2 plane): pollsters poll IMMEDIATELY at prio 1; others lspin.
    if (LAYER == 0){
      if (wave == 0){
        gpoll(watch, 0u, (t >= RING) ? (unsigned)(t - RING + 1) : 0u);   // ring guard
      } else if (wave == 1){
        gpoll(watch, (unsigned)t, 0u);                                   // peers: h0[t-1] ready
        if (lane == 0) __hip_atomic_store(&rdy[0], (unsigned)(t + 1),
                                          __ATOMIC_RELAXED, __HIP_MEMORY_SCOPE_WORKGROUP);
      } else {
        lspin(&rdy[0], (unsigned)(t + 1));
      }
    } else {
      if (wave == 0){
        gpoll(watch, (unsigned)(t + 1), 0u);                             // h0 fresh
        if (lane == 0) __hip_atomic_store(&rdy[0], (unsigned)(t + 1),
                                          __ATOMIC_RELAXED, __HIP_MEMORY_SCOPE_WORKGROUP);
      } else if (wave == 4){
        gpoll(watch, 0u, (unsigned)t);                                   // h1 peers
        if (lane == 0) __hip_atomic_store(&rdy[1], (unsigned)(t + 1),
                                          __ATOMIC_RELAXED, __HIP_MEMORY_SCOPE_WORKGROUP);
      } else if (wave < 4){
        lspin(&rdy[0], (unsigned)(t + 1));
      } else {
        lspin(&rdy[1], (unsigned)(t + 1));
      }
    }
    __builtin_amdgcn_sched_barrier(0);   // keep h loads below the poll

    floatx4 acc[2][4];
    #pragma unroll
    for (int mt = 0; mt < 2; mt++)
      #pragma unroll
      for (int nt = 0; nt < 4; nt++)
        acc[mt][nt] = (floatx4)0.f;

    const unsigned short* h0t = h0h + ((size_t)((LAYER ? t : (t-1)) & (RING-1)) << 16);
    const unsigned short* h1t = h1h + ((size_t)((t-1) & (RING-1)) << 16);

    if constexpr (LAYER == 0){
      #pragma unroll
      for (int ks = 0; ks < NK; ks++){
        const int kb = wave*160 + ks*32;
        const int kk = kb + kq;
        short8 afr[2];
        if (kb < D_){
          #pragma unroll
          for (int mt = 0; mt < 2; mt++)
            afr[mt] = pack8(xraw[ks][mt][0], xraw[ks][mt][1]);
        } else {
          if (t == 0) continue;      // h[-1] = 0: skip (wave-uniform)
          const int hk = kk - D_;
          const unsigned short* p = h0t + ((hk >> 4) << 10) + (hk & 15);
          #pragma unroll
          for (int mt = 0; mt < 2; mt++)
            afr[mt] = *(const short8*)(p + ((half*32 + mt*16 + n15) << 4));
        }
        #pragma unroll
        for (int mt = 0; mt < 2; mt++)
          #pragma unroll
          for (int nt = 0; nt < 4; nt++)
            acc[mt][nt] = __builtin_amdgcn_mfma_f32_16x16x32_bf16(afr[mt], bfr[nt][ks], acc[mt][nt], 0, 0, 0);
      }
    } else {
      #pragma unroll
      for (int ks = 0; ks < NK; ks++){
        const int kb = wave*256 + ks*32;
        if (t == 0 && kb >= KA) continue;   // h1[-1] = 0: skip (wave-uniform)
        const int kk = kb + kq;
        const int hk = (kb < 1024) ? kk : (kk - 1024);
        const unsigned short* sb = (kb < 1024) ? h0t : h1t;
        const unsigned short* p = sb + ((hk >> 4) << 10) + (hk & 15);
        short8 afr[2];
        #pragma unroll
        for (int mt = 0; mt < 2; mt++)
          afr[mt] = *(const short8*)(p + ((half*32 + mt*16 + n15) << 4));
        #pragma unroll
        for (int mt = 0; mt < 2; mt++)
          #pragma unroll
          for (int nt = 0; nt < 4; nt++)
            acc[mt][nt] = __builtin_amdgcn_mfma_f32_16x16x32_bf16(afr[mt], bfr[nt][ks], acc[mt][nt], 0, 0, 0);
      }
    }

    // ---- spill K-slice partials: [n][wave*32+b] so 4 acc rows are one ds_write_b128
    #pragma unroll
    for (int mt = 0; mt < 2; mt++)
      #pragma unroll
      for (int nt = 0; nt < 4; nt++){
        int n  = nt*16 + n15;
        int b0 = mt*16 + (lane >> 4)*4;
        *(floatx4*)(partial + (size_t)n*PS + wave*32 + b0) = acc[mt][nt];
      }
    __syncthreads();

    // ---- gate reduction by ALL 512 threads: one (b, jj) each
    {
      int b = tid >> 4, jj = tid & 15;
      float g[4];
      #pragma unroll
      for (int q = 0; q < 4; q++){
        const float* p = partial + (size_t)(q*16 + jj)*PS + b;
        float s = biasv[q*16 + jj];
        #pragma unroll
        for (int ss = 0; ss < 8; ss++) s += p[ss*32];
        g[q] = s;
      }
      float co = c_st[tid];            // tid == b*16 + jj
      float si = sigm(g[0]), sf = sigm(g[1]), tg = tanh_f(g[2]), so = sigm(g[3]);
      float cn = sf*co + si*tg;
      float hn = so*tanh_f(cn);
      c_st[tid] = cn;
      unsigned hb = (unsigned)f2bf(hn);
      unsigned ob = (unsigned)__shfl_xor((int)hb, 1, 64);   // partner jj^1, same b
      if (!(jj & 1)){
        unsigned pk = hb | (ob << 16);
        // tile layout store: contiguous 1KB per block
        unsigned short* dst = (LAYER ? h1h : h0h)
                            + ((size_t)(t & (RING-1)) << 16)
                            + ((size_t)j << 10) + ((size_t)(half*32 + b) << 4) + jj;
        __hip_atomic_store((unsigned*)dst, pk, __ATOMIC_RELAXED, __HIP_MEMORY_SCOPE_AGENT);
      }
      if (LAYER == 1 && t == T_-1)
        h1f[(size_t)(half*32 + b)*H_ + jbase + jj] = hn;
    }
    __syncthreads();   // all waves drain vmcnt (h stores visible) before the post
    if (tid == 0)
      __hip_atomic_store(seq + (size_t)(half*64 + j)*2 + LAYER, (unsigned)(t + 1),
                         __ATOMIC_RELAXED, __HIP_MEMORY_SCOPE_AGENT);
  }
}

__global__ __launch_bounds__(512, 2) void lstm_pk(
    const float* __restrict__ x,
    const float* __restrict__ Wih0, const float* __restrict__ Whh0,
    const float* __restrict__ bih0, const float* __restrict__ bhh0,
    const float* __restrict__ Wih1, const float* __restrict__ Whh1,
    const float* __restrict__ bih1, const float* __restrict__ bhh1,
    char* __restrict__ ws)
{
  __shared__ __align__(16) float partial[64*PS];   // 66.6 KB
  __shared__ float c_st[512];
  __shared__ float biasv[64];
  __shared__ unsigned rdy[2];

  unsigned* seq       = (unsigned*)ws;                                    // 128 qwords (1 KB)
  unsigned short* h0h = (unsigned short*)(ws + (1<<20));                  // RING x 128KB tiles (8 MB)
  unsigned short* h1h = (unsigned short*)(ws + (1<<20) + RING*B_*H_*2);   // 8 MB
  float* h1f          = (float*)(ws + (1<<20) + 2*(size_t)RING*B_*H_*2);  // [64][1024] fp32

  const int bid = blockIdx.x;
  if (bid < 128){
    run_lstm<0>(x, Wih0, Whh0, bih0, bhh0, seq, h0h, h1h, h1f,
                (bid & 63)*16, bid & 63, bid >> 6, partial, c_st, biasv, rdy);
  } else {
    const int r = bid - 128;
    run_lstm<1>(x, Wih1, Whh1, bih1, bhh1, seq, h0h, h1h, h1f,
                (r & 63)*16, r & 63, r >> 6, partial, c_st, biasv, rdy);
  }
}

__global__ __launch_bounds__(128) void fc_k(
    const float* __restrict__ h1f, const float* __restrict__ Wfc,
    const float* __restrict__ bfc, float* __restrict__ out)
{
  __shared__ float hv[1024];
  int b = blockIdx.x, c = threadIdx.x;
  for (int i = c; i < 1024; i += 128) hv[i] = h1f[(size_t)b*1024 + i];
  __syncthreads();
  const floatx4* w4 = (const floatx4*)(Wfc + (size_t)c*1024);
  const floatx4* h4 = (const floatx4*)hv;
  float acc = 0.f;
  #pragma unroll 8
  for (int k = 0; k < 256; k++){
    floatx4 wv = w4[k];
    floatx4 hh = h4[k];
    acc += wv[0]*hh[0] + wv[1]*hh[1] + wv[2]*hh[2] + wv[3]*hh[3];
  }
  out[(size_t)b*128 + c] = acc + bfc[c];
}

extern "C" void kernel_launch(void* const* d_in, const int* in_sizes, int n_in,
                              void* d_out, int out_size, void* d_ws, size_t ws_size,
                              hipStream_t stream)
{
  const float* x    = (const float*)d_in[0];
  const float* Wih0 = (const float*)d_in[1];
  const float* Whh0 = (const float*)d_in[2];
  const float* bih0 = (const float*)d_in[3];
  const float* bhh0 = (const float*)d_in[4];
  const float* Wih1 = (const float*)d_in[5];
  const float* Whh1 = (const float*)d_in[6];
  const float* bih1 = (const float*)d_in[7];
  const float* bhh1 = (const float*)d_in[8];
  const float* Wfc  = (const float*)d_in[9];
  const float* bfc  = (const float*)d_in[10];

  // zero the seq counters (h ring slots written before first read; h[-1] by predication)
  hipMemsetAsync(d_ws, 0, 4096, stream);

  lstm_pk<<<256, 512, 0, stream>>>(x, Wih0, Whh0, bih0, bhh0, Wih1, Whh1, bih1, bhh1, (char*)d_ws);

  const float* h1f = (const float*)((char*)d_ws + (1<<20) + 2*(size_t)RING*B_*H_*2);
  fc_k<<<64, 128, 0, stream>>>(h1f, Wfc, bfc, (float*)d_out);
}